// Round 4
// baseline (8466.641 us; speedup 1.0000x reference)
//
#include <hip/hip_runtime.h>
#include <math.h>
#include <float.h>
#include <limits.h>

#define BB 64        // batch (== wavefront size)
#define HID 768
#define VOCAB 30000
#define TSTEPS 32
#define CPW 16                     // logit cols per wave
#define NWAVE (VOCAB / CPW)        // 1875
#define NBLK ((NWAVE + 3) / 4)     // 469

// ---------------------------------------------------------------------------
// Closed head stage 1: hid[b][r] = relu(feat[b] . c1W[r] + c1b[r]).
// ---------------------------------------------------------------------------
__global__ __launch_bounds__(256) void kc1(
    const float* __restrict__ feat, const float* __restrict__ c1W,
    const float* __restrict__ c1b, float* __restrict__ hid_ws)
{
    const int q = blockIdx.x, b = blockIdx.y;
    const int wave = threadIdx.x >> 6, lane = threadIdx.x & 63;
    float4 fr[3];
    const float4* frow = (const float4*)(feat + (size_t)b * HID);
    #pragma unroll
    for (int j = 0; j < 3; j++) fr[j] = frow[lane + 64 * j];

    #pragma unroll 2
    for (int rr = 0; rr < 32; rr++) {
        const int r = q * 128 + wave * 32 + rr;
        const float4* w = (const float4*)(c1W + (size_t)r * HID);
        float s = 0.f;
        #pragma unroll
        for (int j = 0; j < 3; j++) {
            float4 wv = w[lane + 64 * j];
            s += fr[j].x * wv.x + fr[j].y * wv.y + fr[j].z * wv.z + fr[j].w * wv.w;
        }
        #pragma unroll
        for (int o = 32; o; o >>= 1) s += __shfl_xor(s, o, 64);
        if (lane == 0) hid_ws[b * 512 + r] = fmaxf(s + c1b[r], 0.f);
    }
}

// Closed head stage 2.
__global__ __launch_bounds__(256) void kc2(
    const float* __restrict__ hid_ws, const float* __restrict__ c2W,
    const float* __restrict__ c2b, float* __restrict__ out)
{
    const int b = blockIdx.x, tid = threadIdx.x;
    __shared__ float red[2][256];
    float s0 = 0.f, s1 = 0.f;
    for (int r = tid; r < 512; r += 256) {
        float hv = hid_ws[b * 512 + r];
        s0 += hv * c2W[r];
        s1 += hv * c2W[512 + r];
    }
    red[0][tid] = s0; red[1][tid] = s1;
    __syncthreads();
    for (int st = 128; st; st >>= 1) {
        if (tid < st) { red[0][tid] += red[0][tid + st]; red[1][tid] += red[1][tid + st]; }
        __syncthreads();
    }
    if (tid == 0) {
        out[b * 2 + 0] = red[0][0] + c2b[0];
        out[b * 2 + 1] = red[1][0] + c2b[1];
    }
}

// ---------------------------------------------------------------------------
// Prep: hA[k][b] = feat[b][k] (h0 = feat, transposed); xT[k][b] = emb[0][k].
// ---------------------------------------------------------------------------
__global__ __launch_bounds__(256) void kprep(
    const float* __restrict__ feat, const float* __restrict__ emb,
    float* __restrict__ hA, float* __restrict__ xT)
{
    int idx = blockIdx.x * 256 + threadIdx.x;   // < 768*64
    int k = idx >> 6, b = idx & 63;
    hA[idx] = feat[b * HID + k];
    xT[idx] = emb[k];
}

// ---------------------------------------------------------------------------
// Fused gates GEMM + LSTM cell. Wave = one hidden index j (0..767); lane =
// batch row m. Weight addresses stay in VGPRs (no readfirstlane) -> VMEM
// broadcast loads, NOT the weak scalar pipe. Barrier-free, no LDS.
// Accumulation order identical to R3 (bit-identical output).
// ---------------------------------------------------------------------------
__global__ __launch_bounds__(256) void kgate(
    int step, const float* __restrict__ xT, const float* __restrict__ hT_in,
    const float* __restrict__ W_ih, const float* __restrict__ W_hh,
    const float* __restrict__ b_ih, const float* __restrict__ b_hh,
    float* __restrict__ cT, float* __restrict__ hT_out)
{
    const int lane = threadIdx.x & 63;
    const int j = (blockIdx.x << 2) | (threadIdx.x >> 6);   // VGPR -> VMEM loads

    float acc[4];
    #pragma unroll
    for (int g = 0; g < 4; g++) acc[g] = b_ih[g * HID + j] + b_hh[g * HID + j];

    // x @ W_ih.T contribution
    for (int k0 = 0; k0 < HID; k0 += 16) {
        float xv[16];
        #pragma unroll
        for (int kk = 0; kk < 16; kk++) xv[kk] = xT[(k0 + kk) * 64 + lane];
        #pragma unroll
        for (int g = 0; g < 4; g++) {
            const float4* w4 = (const float4*)(W_ih + (size_t)(g * HID + j) * HID + k0);
            float4 wa = w4[0], wb = w4[1], wc = w4[2], wd = w4[3];
            acc[g] = fmaf(xv[0],  wa.x, acc[g]); acc[g] = fmaf(xv[1],  wa.y, acc[g]);
            acc[g] = fmaf(xv[2],  wa.z, acc[g]); acc[g] = fmaf(xv[3],  wa.w, acc[g]);
            acc[g] = fmaf(xv[4],  wb.x, acc[g]); acc[g] = fmaf(xv[5],  wb.y, acc[g]);
            acc[g] = fmaf(xv[6],  wb.z, acc[g]); acc[g] = fmaf(xv[7],  wb.w, acc[g]);
            acc[g] = fmaf(xv[8],  wc.x, acc[g]); acc[g] = fmaf(xv[9],  wc.y, acc[g]);
            acc[g] = fmaf(xv[10], wc.z, acc[g]); acc[g] = fmaf(xv[11], wc.w, acc[g]);
            acc[g] = fmaf(xv[12], wd.x, acc[g]); acc[g] = fmaf(xv[13], wd.y, acc[g]);
            acc[g] = fmaf(xv[14], wd.z, acc[g]); acc[g] = fmaf(xv[15], wd.w, acc[g]);
        }
    }
    // h @ W_hh.T contribution
    for (int k0 = 0; k0 < HID; k0 += 16) {
        float hv[16];
        #pragma unroll
        for (int kk = 0; kk < 16; kk++) hv[kk] = hT_in[(k0 + kk) * 64 + lane];
        #pragma unroll
        for (int g = 0; g < 4; g++) {
            const float4* w4 = (const float4*)(W_hh + (size_t)(g * HID + j) * HID + k0);
            float4 wa = w4[0], wb = w4[1], wc = w4[2], wd = w4[3];
            acc[g] = fmaf(hv[0],  wa.x, acc[g]); acc[g] = fmaf(hv[1],  wa.y, acc[g]);
            acc[g] = fmaf(hv[2],  wa.z, acc[g]); acc[g] = fmaf(hv[3],  wa.w, acc[g]);
            acc[g] = fmaf(hv[4],  wb.x, acc[g]); acc[g] = fmaf(hv[5],  wb.y, acc[g]);
            acc[g] = fmaf(hv[6],  wb.z, acc[g]); acc[g] = fmaf(hv[7],  wb.w, acc[g]);
            acc[g] = fmaf(hv[8],  wc.x, acc[g]); acc[g] = fmaf(hv[9],  wc.y, acc[g]);
            acc[g] = fmaf(hv[10], wc.z, acc[g]); acc[g] = fmaf(hv[11], wc.w, acc[g]);
            acc[g] = fmaf(hv[12], wd.x, acc[g]); acc[g] = fmaf(hv[13], wd.y, acc[g]);
            acc[g] = fmaf(hv[14], wd.z, acc[g]); acc[g] = fmaf(hv[15], wd.w, acc[g]);
        }
    }

    float cprev = (step == 0) ? 0.f : cT[j * 64 + lane];
    float ig = 1.f / (1.f + expf(-acc[0]));
    float fg = 1.f / (1.f + expf(-acc[1]));
    float gg = tanhf(acc[2]);
    float og = 1.f / (1.f + expf(-acc[3]));
    float cn = fg * cprev + ig * gg;
    float hn = og * tanhf(cn);
    cT[j * 64 + lane] = cn;
    hT_out[j * 64 + lane] = hn;
}

// ---------------------------------------------------------------------------
// Logits GEMV-batch + per-wave argmax. Wave wid owns 16 cols; lane = batch
// row m. Weight addresses in VGPRs -> VMEM dwordx4 broadcast loads. No LDS,
// no barriers. Per-logit FMA chain k ascending (bit-identical).
// ---------------------------------------------------------------------------
__global__ __launch_bounds__(256) void klog(
    const float* __restrict__ hT, const float* __restrict__ outW,
    const float* __restrict__ outb, float* __restrict__ pval, int* __restrict__ pidx)
{
    const int lane = threadIdx.x & 63;
    const int wid = (blockIdx.x << 2) | (threadIdx.x >> 6);  // VGPR -> VMEM loads
    if (wid >= NWAVE) return;
    const int n0 = wid * CPW;

    float acc[CPW];
    #pragma unroll
    for (int c = 0; c < CPW; c++) acc[c] = 0.f;

    float hv[16], hn[16];
    #pragma unroll
    for (int kk = 0; kk < 16; kk++) hv[kk] = hT[kk * 64 + lane];

    for (int k0 = 0; k0 < HID; k0 += 16) {
        if (k0 + 16 < HID) {
            #pragma unroll
            for (int kk = 0; kk < 16; kk++) hn[kk] = hT[(k0 + 16 + kk) * 64 + lane];
        }
        #pragma unroll
        for (int c = 0; c < CPW; c++) {
            const float4* w4 = (const float4*)(outW + (size_t)(n0 + c) * HID + k0);
            float4 wa = w4[0], wb = w4[1], wc = w4[2], wd = w4[3];
            acc[c] = fmaf(hv[0],  wa.x, acc[c]); acc[c] = fmaf(hv[1],  wa.y, acc[c]);
            acc[c] = fmaf(hv[2],  wa.z, acc[c]); acc[c] = fmaf(hv[3],  wa.w, acc[c]);
            acc[c] = fmaf(hv[4],  wb.x, acc[c]); acc[c] = fmaf(hv[5],  wb.y, acc[c]);
            acc[c] = fmaf(hv[6],  wb.z, acc[c]); acc[c] = fmaf(hv[7],  wb.w, acc[c]);
            acc[c] = fmaf(hv[8],  wc.x, acc[c]); acc[c] = fmaf(hv[9],  wc.y, acc[c]);
            acc[c] = fmaf(hv[10], wc.z, acc[c]); acc[c] = fmaf(hv[11], wc.w, acc[c]);
            acc[c] = fmaf(hv[12], wd.x, acc[c]); acc[c] = fmaf(hv[13], wd.y, acc[c]);
            acc[c] = fmaf(hv[14], wd.z, acc[c]); acc[c] = fmaf(hv[15], wd.w, acc[c]);
        }
        if (k0 + 16 < HID) {
            #pragma unroll
            for (int kk = 0; kk < 16; kk++) hv[kk] = hn[kk];
        }
    }

    // per-lane argmax over this wave's cols (ascending -> first occurrence)
    float bv = -FLT_MAX; int bi = INT_MAX;
    #pragma unroll
    for (int c = 0; c < CPW; c++) {
        float v = acc[c] + outb[n0 + c];
        if (v > bv) { bv = v; bi = n0 + c; }
    }
    pval[lane * NWAVE + wid] = bv;
    pidx[lane * NWAVE + wid] = bi;
}

// ---------------------------------------------------------------------------
// Finalize token for batch row b; gather xT = emb[tok]^T for the next step.
// ---------------------------------------------------------------------------
__global__ __launch_bounds__(256) void kfin(
    int step, const float* __restrict__ pval, const int* __restrict__ pidx,
    const float* __restrict__ emb, float* __restrict__ xT, float* __restrict__ gen)
{
    const int b = blockIdx.x, tid = threadIdx.x;
    __shared__ float sv[256];
    __shared__ int   si[256];
    __shared__ int   stok;
    float bv = -FLT_MAX; int bi = INT_MAX;
    for (int p = tid; p < NWAVE; p += 256) {
        float v = pval[b * NWAVE + p]; int ix = pidx[b * NWAVE + p];
        if (v > bv || (v == bv && ix < bi)) { bv = v; bi = ix; }
    }
    sv[tid] = bv; si[tid] = bi;
    __syncthreads();
    for (int st = 128; st; st >>= 1) {
        if (tid < st) {
            float v = sv[tid + st]; int ix = si[tid + st];
            if (v > sv[tid] || (v == sv[tid] && ix < si[tid])) { sv[tid] = v; si[tid] = ix; }
        }
        __syncthreads();
    }
    if (tid == 0) {
        stok = si[0];
        gen[b * TSTEPS + step] = (float)si[0];
    }
    __syncthreads();
    const int tok = stok;
    for (int k = tid; k < HID; k += 256)
        xT[k * 64 + b] = emb[(size_t)tok * HID + k];
}

// ---------------------------------------------------------------------------
extern "C" void kernel_launch(void* const* d_in, const int* in_sizes, int n_in,
                              void* d_out, int out_size, void* d_ws, size_t ws_size,
                              hipStream_t stream)
{
    const float* feat = (const float*)d_in[0];
    const float* emb  = (const float*)d_in[1];
    const float* W_ih = (const float*)d_in[2];
    const float* W_hh = (const float*)d_in[3];
    const float* b_ih = (const float*)d_in[4];
    const float* b_hh = (const float*)d_in[5];
    const float* outW = (const float*)d_in[6];
    const float* outb = (const float*)d_in[7];
    const float* c1W  = (const float*)d_in[8];
    const float* c1b  = (const float*)d_in[9];
    const float* c2W  = (const float*)d_in[10];
    const float* c2b  = (const float*)d_in[11];
    (void)in_sizes; (void)n_in; (void)out_size; (void)ws_size;

    float* out = (float*)d_out;
    float* gen = out + BB * 2;                  // generated (64x32), as floats

    float* ws     = (float*)d_ws;
    float* hA     = ws;                         // 768*64
    float* hB     = hA + HID * 64;              // 768*64
    float* cT     = hB + HID * 64;              // 768*64
    float* xT     = cT + HID * 64;              // 768*64
    float* pval   = xT + HID * 64;              // 64*1875
    int*   pidx   = (int*)(pval + BB * NWAVE);  // 64*1875
    float* hid_ws = (float*)(pidx + BB * NWAVE);// 64*512

    kc1<<<dim3(4, BB), 256, 0, stream>>>(feat, c1W, c1b, hid_ws);
    kc2<<<BB, 256, 0, stream>>>(hid_ws, c2W, c2b, out);
    kprep<<<dim3(HID * 64 / 256), 256, 0, stream>>>(feat, emb, hA, xT);

    for (int t = 0; t < TSTEPS; t++) {
        const float* h_in = (t & 1) ? hB : hA;
        float*       h_out = (t & 1) ? hA : hB;
        kgate<<<dim3(192), 256, 0, stream>>>(t, xT, h_in, W_ih, W_hh, b_ih, b_hh, cT, h_out);
        klog<<<dim3(NBLK), 256, 0, stream>>>(h_out, outW, outb, pval, pidx);
        kfin<<<BB, 256, 0, stream>>>(t, pval, pidx, emb, xT, gen);
    }
}

// Round 5
// 3770.639 us; speedup vs baseline: 2.2454x; 2.2454x over previous
//
#include <hip/hip_runtime.h>
#include <math.h>
#include <float.h>
#include <limits.h>

#define BB 64        // batch (== wavefront size)
#define HID 768
#define VOCAB 30000
#define NG 3072      // 4*HID
#define TSTEPS 32
#define NB_LOG 235   // ceil(30000/128)

// ---------------------------------------------------------------------------
// Closed head stage 1: hid[b][r] = relu(feat[b] . c1W[r] + c1b[r]).
// ---------------------------------------------------------------------------
__global__ __launch_bounds__(256) void kc1(
    const float* __restrict__ feat, const float* __restrict__ c1W,
    const float* __restrict__ c1b, float* __restrict__ hid_ws)
{
    const int q = blockIdx.x, b = blockIdx.y;
    const int wave = threadIdx.x >> 6, lane = threadIdx.x & 63;
    float4 fr[3];
    const float4* frow = (const float4*)(feat + (size_t)b * HID);
    #pragma unroll
    for (int j = 0; j < 3; j++) fr[j] = frow[lane + 64 * j];

    #pragma unroll 2
    for (int rr = 0; rr < 32; rr++) {
        const int r = q * 128 + wave * 32 + rr;
        const float4* w = (const float4*)(c1W + (size_t)r * HID);
        float s = 0.f;
        #pragma unroll
        for (int j = 0; j < 3; j++) {
            float4 wv = w[lane + 64 * j];
            s += fr[j].x * wv.x + fr[j].y * wv.y + fr[j].z * wv.z + fr[j].w * wv.w;
        }
        #pragma unroll
        for (int o = 32; o; o >>= 1) s += __shfl_xor(s, o, 64);
        if (lane == 0) hid_ws[b * 512 + r] = fmaxf(s + c1b[r], 0.f);
    }
}

// Closed head stage 2.
__global__ __launch_bounds__(256) void kc2(
    const float* __restrict__ hid_ws, const float* __restrict__ c2W,
    const float* __restrict__ c2b, float* __restrict__ out)
{
    const int b = blockIdx.x, tid = threadIdx.x;
    __shared__ float red[2][256];
    float s0 = 0.f, s1 = 0.f;
    for (int r = tid; r < 512; r += 256) {
        float hv = hid_ws[b * 512 + r];
        s0 += hv * c2W[r];
        s1 += hv * c2W[512 + r];
    }
    red[0][tid] = s0; red[1][tid] = s1;
    __syncthreads();
    for (int st = 128; st; st >>= 1) {
        if (tid < st) { red[0][tid] += red[0][tid + st]; red[1][tid] += red[1][tid + st]; }
        __syncthreads();
    }
    if (tid == 0) {
        out[b * 2 + 0] = red[0][0] + c2b[0];
        out[b * 2 + 1] = red[1][0] + c2b[1];
    }
}

// ---------------------------------------------------------------------------
// Prep: hT[k][b] = feat[b][k]  (transposed h0 for klog).
// ---------------------------------------------------------------------------
__global__ __launch_bounds__(256) void kprep(
    const float* __restrict__ feat, float* __restrict__ hT)
{
    int idx = blockIdx.x * 256 + threadIdx.x;   // < 768*64
    int k = idx >> 6, b = idx & 63;
    hT[idx] = feat[b * HID + k];
}

// ---------------------------------------------------------------------------
// Gates GEMM partial (R2 structure, proven): grid (48,4). nc = 64-col chunk
// of 3072; ks<2: x = emb[tok] @ W_ih halves; ks>=2: h @ W_hh halves.
// ---------------------------------------------------------------------------
__global__ __launch_bounds__(256) void kg1(
    int step, const int* __restrict__ tok_ws, const float* __restrict__ emb,
    const float* __restrict__ W_ih, const float* __restrict__ W_hh,
    const float* __restrict__ h_in, float* __restrict__ gpart)
{
    const int tid = threadIdx.x;
    const int nc = blockIdx.x;   // 0..47
    const int ks = blockIdx.y;   // 0..3
    __shared__ int tok_lds[BB];
    __shared__ float as[32][68];
    __shared__ float wsl[32][68];

    if (ks < 2 && tid < BB)
        tok_lds[tid] = (step == 0) ? 0 : tok_ws[tid];
    __syncthreads();

    const int ty = tid >> 4, tx = tid & 15;
    float acc[4][4] = {};

    for (int k0 = 0; k0 < 384; k0 += 32) {
        for (int i = tid; i < 512; i += 256) {   // A: 64 rows x 32 k
            int r = i >> 3, kq = i & 7;
            const float* base = (ks < 2)
                ? (emb + (size_t)tok_lds[r] * HID + ks * 384)
                : (h_in + (size_t)r * HID + (ks - 2) * 384);
            float4 v = *(const float4*)(base + k0 + kq * 4);
            as[kq*4+0][r] = v.x; as[kq*4+1][r] = v.y;
            as[kq*4+2][r] = v.z; as[kq*4+3][r] = v.w;
        }
        for (int i = tid; i < 512; i += 256) {   // W: 64 cols x 32 k
            int c = i >> 3, kq = i & 7;
            int gcol = nc * 64 + c;
            const float* wb = (ks < 2)
                ? (W_ih + (size_t)gcol * HID + ks * 384)
                : (W_hh + (size_t)gcol * HID + (ks - 2) * 384);
            float4 v = *(const float4*)(wb + k0 + kq * 4);
            wsl[kq*4+0][c] = v.x; wsl[kq*4+1][c] = v.y;
            wsl[kq*4+2][c] = v.z; wsl[kq*4+3][c] = v.w;
        }
        __syncthreads();
        #pragma unroll
        for (int kk = 0; kk < 32; kk++) {
            float4 av = *(const float4*)&as[kk][ty * 4];
            float4 wv = *(const float4*)&wsl[kk][tx * 4];
            acc[0][0] += av.x*wv.x; acc[0][1] += av.x*wv.y; acc[0][2] += av.x*wv.z; acc[0][3] += av.x*wv.w;
            acc[1][0] += av.y*wv.x; acc[1][1] += av.y*wv.y; acc[1][2] += av.y*wv.z; acc[1][3] += av.y*wv.w;
            acc[2][0] += av.z*wv.x; acc[2][1] += av.z*wv.y; acc[2][2] += av.z*wv.z; acc[2][3] += av.z*wv.w;
            acc[3][0] += av.w*wv.x; acc[3][1] += av.w*wv.y; acc[3][2] += av.w*wv.z; acc[3][3] += av.w*wv.w;
        }
        __syncthreads();
    }
    #pragma unroll
    for (int i = 0; i < 4; i++) {
        float4 v = make_float4(acc[i][0], acc[i][1], acc[i][2], acc[i][3]);
        *(float4*)(gpart + ((size_t)(ks * BB) + ty * 4 + i) * NG + nc * 64 + tx * 4) = v;
    }
}

// ---------------------------------------------------------------------------
// Cell: sum 4 K-partials (fixed order) + biases, LSTM update. Writes h both
// b-major (for kg1) and transposed hT[k][b] (for klog).
// ---------------------------------------------------------------------------
__global__ __launch_bounds__(256) void kc(
    int step, const float* __restrict__ gpart, const float* __restrict__ b_ih,
    const float* __restrict__ b_hh, float* __restrict__ cbuf,
    float* __restrict__ h_out, float* __restrict__ hT)
{
    int idx = blockIdx.x * 256 + threadIdx.x;   // < 64*768
    int b = idx / HID, j = idx % HID;
    float g4[4];
    #pragma unroll
    for (int g = 0; g < 4; g++) {
        int col = g * HID + j;
        float s = b_ih[col] + b_hh[col];
        #pragma unroll
        for (int ksd = 0; ksd < 4; ksd++)
            s += gpart[((size_t)ksd * BB + b) * NG + col];
        g4[g] = s;
    }
    float cprev = (step == 0) ? 0.f : cbuf[idx];
    float ig = 1.f / (1.f + expf(-g4[0]));
    float fg = 1.f / (1.f + expf(-g4[1]));
    float gg = tanhf(g4[2]);
    float og = 1.f / (1.f + expf(-g4[3]));
    float cn = fg * cprev + ig * gg;
    float hn = og * tanhf(cn);
    cbuf[idx] = cn;
    h_out[idx] = hn;
    hT[j * 64 + b] = hn;
}

// ---------------------------------------------------------------------------
// Logits GEMM + fused argmax partial. 235 blocks, tile M=64 x N=128.
// 256 threads = 2 K-teams (k<384 / k>=384) of 128 threads, each with an
// 8x8 register tile (0.25 LDS-words/FMA = LDS balance point). BK=32,
// register-prefetch pipeline. Epilogue: team-sum + bias + argmax in LDS.
// Chain: (team0 k-ascending) + (team1 k-ascending) + bias  — deterministic.
// ---------------------------------------------------------------------------
__global__ __launch_bounds__(256) void klog(
    const float* __restrict__ hT, const float* __restrict__ outW,
    const float* __restrict__ outb, float* __restrict__ pval, int* __restrict__ pidx)
{
    // LDS: As[2][32][68] (4352 f) | Bs[2][32][132] (8448 f); epilogue overlays
    // L[64*128] (8192 f) on the same buffer.
    __shared__ float SMEM[12800];
    __shared__ float fvv[256];
    __shared__ int   fii[256];
    float* As = SMEM;            // team*2176 + k*68 + b
    float* Bs = SMEM + 4352;     // team*4224 + k*132 + n

    const int tid  = threadIdx.x;
    const int team = tid >> 7;          // 0: k<384, 1: k>=384
    const int t128 = tid & 127;
    const int ty = t128 >> 4;           // 0..7  -> rows ty*8..+7
    const int tx = t128 & 15;           // 0..15 -> cols tx*8..+7
    const int cb = blockIdx.x;
    const int c0 = cb * 128;
    const int tk0 = team * 384;

    const int gc = (c0 + t128 < VOCAB) ? (c0 + t128) : (VOCAB - 1);
    const float* wrow = outW + (size_t)gc * HID + tk0;
    const float* arow = hT + (size_t)tk0 * 64 + tx * 4;

    float4 pa[4], pb[8];
    #pragma unroll
    for (int q = 0; q < 4; q++)
        pa[q] = *(const float4*)(arow + (q * 8 + ty) * 64);
    #pragma unroll
    for (int kq = 0; kq < 8; kq++)
        pb[kq] = *(const float4*)(wrow + kq * 4);

    float acc[8][8];
    #pragma unroll
    for (int i = 0; i < 8; i++)
        #pragma unroll
        for (int j = 0; j < 8; j++) acc[i][j] = 0.f;

    float* Ast = As + team * 2176;
    float* Bst = Bs + team * 4224;

    for (int ch = 0; ch < 12; ch++) {
        __syncthreads();   // previous chunk's readers done
        #pragma unroll
        for (int q = 0; q < 4; q++)
            *(float4*)(Ast + (q * 8 + ty) * 68 + tx * 4) = pa[q];
        #pragma unroll
        for (int kq = 0; kq < 8; kq++) {
            Bst[(kq * 4 + 0) * 132 + t128] = pb[kq].x;
            Bst[(kq * 4 + 1) * 132 + t128] = pb[kq].y;
            Bst[(kq * 4 + 2) * 132 + t128] = pb[kq].z;
            Bst[(kq * 4 + 3) * 132 + t128] = pb[kq].w;
        }
        __syncthreads();   // LDS ready
        if (ch < 11) {
            const int off = (ch + 1) * 32;
            #pragma unroll
            for (int q = 0; q < 4; q++)
                pa[q] = *(const float4*)(arow + (off + q * 8 + ty) * 64);
            #pragma unroll
            for (int kq = 0; kq < 8; kq++)
                pb[kq] = *(const float4*)(wrow + off + kq * 4);
        }
        #pragma unroll 8
        for (int kk = 0; kk < 32; kk++) {
            const float* Ab = Ast + kk * 68 + ty * 8;
            const float* Bb = Bst + kk * 132 + tx * 8;
            float4 a0 = *(const float4*)Ab, a1 = *(const float4*)(Ab + 4);
            float4 b0 = *(const float4*)Bb, b1 = *(const float4*)(Bb + 4);
            float av[8] = {a0.x,a0.y,a0.z,a0.w,a1.x,a1.y,a1.z,a1.w};
            float bv[8] = {b0.x,b0.y,b0.z,b0.w,b1.x,b1.y,b1.z,b1.w};
            #pragma unroll
            for (int i = 0; i < 8; i++)
                #pragma unroll
                for (int j = 0; j < 8; j++)
                    acc[i][j] = fmaf(av[i], bv[j], acc[i][j]);
        }
    }

    // ---- epilogue: team combine + bias + argmax ----
    float* L = SMEM;   // 64 x 128
    __syncthreads();
    if (team == 0) {
        #pragma unroll
        for (int i = 0; i < 8; i++)
            #pragma unroll
            for (int j = 0; j < 8; j++)
                L[(ty * 8 + i) * 128 + tx * 8 + j] = acc[i][j];
    }
    __syncthreads();
    if (team == 1) {
        #pragma unroll
        for (int i = 0; i < 8; i++)
            #pragma unroll
            for (int j = 0; j < 8; j++)
                L[(ty * 8 + i) * 128 + tx * 8 + j] += acc[i][j];
    }
    __syncthreads();

    {   // thread tid: batch row b = tid>>2, col segment seg = tid&3 (32 cols)
        const int b = tid >> 2, seg = tid & 3;
        float bvv = -FLT_MAX; int bii = INT_MAX;
        #pragma unroll 8
        for (int cc = 0; cc < 32; cc++) {
            int col = seg * 32 + cc;
            int c = c0 + col;
            if (c < VOCAB) {
                float v = L[b * 128 + col] + outb[c];
                if (v > bvv) { bvv = v; bii = c; }   // cc ascending -> first occurrence
            }
        }
        fvv[tid] = bvv; fii[tid] = bii;
    }
    __syncthreads();
    if (tid < BB) {
        float bvv = -FLT_MAX; int bii = INT_MAX;
        #pragma unroll
        for (int s = 0; s < 4; s++) {
            float v = fvv[tid * 4 + s]; int ix = fii[tid * 4 + s];
            if (v > bvv || (v == bvv && ix < bii)) { bvv = v; bii = ix; }
        }
        pval[tid * NB_LOG + cb] = bvv;
        pidx[tid * NB_LOG + cb] = bii;
    }
}

// ---------------------------------------------------------------------------
// Finalize token for batch row b.
// ---------------------------------------------------------------------------
__global__ __launch_bounds__(256) void kfin(
    int step, const float* __restrict__ pval, const int* __restrict__ pidx,
    int* __restrict__ tok_ws, float* __restrict__ gen)
{
    const int b = blockIdx.x, tid = threadIdx.x;
    __shared__ float sv[256];
    __shared__ int   si[256];
    float bv = -FLT_MAX; int bi = INT_MAX;
    for (int p = tid; p < NB_LOG; p += 256) {
        float v = pval[b * NB_LOG + p]; int ix = pidx[b * NB_LOG + p];
        if (v > bv || (v == bv && ix < bi)) { bv = v; bi = ix; }
    }
    sv[tid] = bv; si[tid] = bi;
    __syncthreads();
    for (int st = 128; st; st >>= 1) {
        if (tid < st) {
            float v = sv[tid + st]; int ix = si[tid + st];
            if (v > sv[tid] || (v == sv[tid] && ix < si[tid])) { sv[tid] = v; si[tid] = ix; }
        }
        __syncthreads();
    }
    if (tid == 0) {
        tok_ws[b] = si[0];
        gen[b * TSTEPS + step] = (float)si[0];
    }
}

// ---------------------------------------------------------------------------
extern "C" void kernel_launch(void* const* d_in, const int* in_sizes, int n_in,
                              void* d_out, int out_size, void* d_ws, size_t ws_size,
                              hipStream_t stream)
{
    const float* feat = (const float*)d_in[0];
    const float* emb  = (const float*)d_in[1];
    const float* W_ih = (const float*)d_in[2];
    const float* W_hh = (const float*)d_in[3];
    const float* b_ih = (const float*)d_in[4];
    const float* b_hh = (const float*)d_in[5];
    const float* outW = (const float*)d_in[6];
    const float* outb = (const float*)d_in[7];
    const float* c1W  = (const float*)d_in[8];
    const float* c1b  = (const float*)d_in[9];
    const float* c2W  = (const float*)d_in[10];
    const float* c2b  = (const float*)d_in[11];
    (void)in_sizes; (void)n_in; (void)out_size; (void)ws_size;

    float* out = (float*)d_out;
    float* gen = out + BB * 2;                  // generated (64x32), as floats

    float* ws     = (float*)d_ws;
    float* hbuf   = ws;                          // 64*768  (b-major h)
    float* cbuf   = hbuf + BB * HID;             // 64*768
    float* hT     = cbuf + BB * HID;             // 768*64  (k-major h)
    float* gpart  = hT + HID * 64;               // 4*64*3072
    float* pval   = gpart + 4 * (size_t)BB * NG; // 64*235
    int*   pidx   = (int*)(pval + BB * NB_LOG);  // 64*235
    int*   tok    = pidx + BB * NB_LOG;          // 64
    float* hid_ws = (float*)(tok + BB);          // 64*512

    kc1<<<dim3(4, BB), 256, 0, stream>>>(feat, c1W, c1b, hid_ws);
    kc2<<<BB, 256, 0, stream>>>(hid_ws, c2W, c2b, out);
    kprep<<<dim3(HID * 64 / 256), 256, 0, stream>>>(feat, hT);

    for (int t = 0; t < TSTEPS; t++) {
        const float* h_in = (t == 0) ? feat : hbuf;
        kg1<<<dim3(48, 4), 256, 0, stream>>>(t, tok, emb, W_ih, W_hh, h_in, gpart);
        kc<<<dim3(192), 256, 0, stream>>>(t, gpart, b_ih, b_hh, cbuf, hbuf, hT);
        klog<<<dim3(NB_LOG), 256, 0, stream>>>(hT, outW, outb, pval, pidx);
        kfin<<<BB, 256, 0, stream>>>(t, pval, pidx, tok, gen);
    }
}

// Round 6
// 2892.802 us; speedup vs baseline: 2.9268x; 1.3035x over previous
//
#include <hip/hip_runtime.h>
#include <math.h>
#include <float.h>
#include <limits.h>

#define BB 64        // batch (== wavefront size)
#define HID 768
#define VOCAB 30000
#define NG 3072      // 4*HID
#define TSTEPS 32
#define NB_LOG 235   // ceil(30000/128)
#define KSPLIT 8     // kg1 K-split (gates)

// ---------------------------------------------------------------------------
// Closed head stage 1: hid[b][r] = relu(feat[b] . c1W[r] + c1b[r]).
// ---------------------------------------------------------------------------
__global__ __launch_bounds__(256) void kc1(
    const float* __restrict__ feat, const float* __restrict__ c1W,
    const float* __restrict__ c1b, float* __restrict__ hid_ws)
{
    const int q = blockIdx.x, b = blockIdx.y;
    const int wave = threadIdx.x >> 6, lane = threadIdx.x & 63;
    float4 fr[3];
    const float4* frow = (const float4*)(feat + (size_t)b * HID);
    #pragma unroll
    for (int j = 0; j < 3; j++) fr[j] = frow[lane + 64 * j];

    #pragma unroll 2
    for (int rr = 0; rr < 32; rr++) {
        const int r = q * 128 + wave * 32 + rr;
        const float4* w = (const float4*)(c1W + (size_t)r * HID);
        float s = 0.f;
        #pragma unroll
        for (int j = 0; j < 3; j++) {
            float4 wv = w[lane + 64 * j];
            s += fr[j].x * wv.x + fr[j].y * wv.y + fr[j].z * wv.z + fr[j].w * wv.w;
        }
        #pragma unroll
        for (int o = 32; o; o >>= 1) s += __shfl_xor(s, o, 64);
        if (lane == 0) hid_ws[b * 512 + r] = fmaxf(s + c1b[r], 0.f);
    }
}

// Closed head stage 2.
__global__ __launch_bounds__(256) void kc2(
    const float* __restrict__ hid_ws, const float* __restrict__ c2W,
    const float* __restrict__ c2b, float* __restrict__ out)
{
    const int b = blockIdx.x, tid = threadIdx.x;
    __shared__ float red[2][256];
    float s0 = 0.f, s1 = 0.f;
    for (int r = tid; r < 512; r += 256) {
        float hv = hid_ws[b * 512 + r];
        s0 += hv * c2W[r];
        s1 += hv * c2W[512 + r];
    }
    red[0][tid] = s0; red[1][tid] = s1;
    __syncthreads();
    for (int st = 128; st; st >>= 1) {
        if (tid < st) { red[0][tid] += red[0][tid + st]; red[1][tid] += red[1][tid + st]; }
        __syncthreads();
    }
    if (tid == 0) {
        out[b * 2 + 0] = red[0][0] + c2b[0];
        out[b * 2 + 1] = red[1][0] + c2b[1];
    }
}

// ---------------------------------------------------------------------------
// Prep: hT[k][b] = feat[b][k]  (transposed h0 for klog).
// ---------------------------------------------------------------------------
__global__ __launch_bounds__(256) void kprep(
    const float* __restrict__ feat, float* __restrict__ hT)
{
    int idx = blockIdx.x * 256 + threadIdx.x;   // < 768*64
    int k = idx >> 6, b = idx & 63;
    hT[idx] = feat[b * HID + k];
}

// ---------------------------------------------------------------------------
// Gates GEMM partial: grid (48, 8). nc = 64-col chunk of 3072; ks<4:
// x = emb[tok] @ W_ih K-quarter; ks>=4: h @ W_hh K-quarter. K=192/block.
// ---------------------------------------------------------------------------
__global__ __launch_bounds__(256) void kg1(
    int step, const int* __restrict__ tok_ws, const float* __restrict__ emb,
    const float* __restrict__ W_ih, const float* __restrict__ W_hh,
    const float* __restrict__ h_in, float* __restrict__ gpart)
{
    const int tid = threadIdx.x;
    const int nc = blockIdx.x;   // 0..47
    const int ks = blockIdx.y;   // 0..7
    __shared__ int tok_lds[BB];
    __shared__ float as[32][68];
    __shared__ float wsl[32][68];

    if (ks < 4 && tid < BB)
        tok_lds[tid] = (step == 0) ? 0 : tok_ws[tid];
    __syncthreads();

    const int ty = tid >> 4, tx = tid & 15;
    float acc[4][4] = {};

    for (int k0 = 0; k0 < 192; k0 += 32) {
        for (int i = tid; i < 512; i += 256) {   // A: 64 rows x 32 k
            int r = i >> 3, kq = i & 7;
            const float* base = (ks < 4)
                ? (emb + (size_t)tok_lds[r] * HID + ks * 192)
                : (h_in + (size_t)r * HID + (ks - 4) * 192);
            float4 v = *(const float4*)(base + k0 + kq * 4);
            as[kq*4+0][r] = v.x; as[kq*4+1][r] = v.y;
            as[kq*4+2][r] = v.z; as[kq*4+3][r] = v.w;
        }
        for (int i = tid; i < 512; i += 256) {   // W: 64 cols x 32 k
            int c = i >> 3, kq = i & 7;
            int gcol = nc * 64 + c;
            const float* wb = (ks < 4)
                ? (W_ih + (size_t)gcol * HID + ks * 192)
                : (W_hh + (size_t)gcol * HID + (ks - 4) * 192);
            float4 v = *(const float4*)(wb + k0 + kq * 4);
            wsl[kq*4+0][c] = v.x; wsl[kq*4+1][c] = v.y;
            wsl[kq*4+2][c] = v.z; wsl[kq*4+3][c] = v.w;
        }
        __syncthreads();
        #pragma unroll
        for (int kk = 0; kk < 32; kk++) {
            float4 av = *(const float4*)&as[kk][ty * 4];
            float4 wv = *(const float4*)&wsl[kk][tx * 4];
            acc[0][0] += av.x*wv.x; acc[0][1] += av.x*wv.y; acc[0][2] += av.x*wv.z; acc[0][3] += av.x*wv.w;
            acc[1][0] += av.y*wv.x; acc[1][1] += av.y*wv.y; acc[1][2] += av.y*wv.z; acc[1][3] += av.y*wv.w;
            acc[2][0] += av.z*wv.x; acc[2][1] += av.z*wv.y; acc[2][2] += av.z*wv.z; acc[2][3] += av.z*wv.w;
            acc[3][0] += av.w*wv.x; acc[3][1] += av.w*wv.y; acc[3][2] += av.w*wv.z; acc[3][3] += av.w*wv.w;
        }
        __syncthreads();
    }
    #pragma unroll
    for (int i = 0; i < 4; i++) {
        float4 v = make_float4(acc[i][0], acc[i][1], acc[i][2], acc[i][3]);
        *(float4*)(gpart + ((size_t)(ks * BB) + ty * 4 + i) * NG + nc * 64 + tx * 4) = v;
    }
}

// ---------------------------------------------------------------------------
// Cell: sum 8 K-partials (fixed order) + biases, LSTM update. Writes h both
// b-major (for kg1) and transposed hT[k][b] (for klog).
// ---------------------------------------------------------------------------
__global__ __launch_bounds__(256) void kc(
    int step, const float* __restrict__ gpart, const float* __restrict__ b_ih,
    const float* __restrict__ b_hh, float* __restrict__ cbuf,
    float* __restrict__ h_out, float* __restrict__ hT)
{
    int idx = blockIdx.x * 256 + threadIdx.x;   // < 64*768
    int b = idx / HID, j = idx % HID;
    float g4[4];
    #pragma unroll
    for (int g = 0; g < 4; g++) {
        int col = g * HID + j;
        float s = b_ih[col] + b_hh[col];
        #pragma unroll
        for (int ksd = 0; ksd < KSPLIT; ksd++)
            s += gpart[((size_t)ksd * BB + b) * NG + col];
        g4[g] = s;
    }
    float cprev = (step == 0) ? 0.f : cbuf[idx];
    float ig = 1.f / (1.f + expf(-g4[0]));
    float fg = 1.f / (1.f + expf(-g4[1]));
    float gg = tanhf(g4[2]);
    float og = 1.f / (1.f + expf(-g4[3]));
    float cn = fg * cprev + ig * gg;
    float hn = og * tanhf(cn);
    cbuf[idx] = cn;
    h_out[idx] = hn;
    hT[j * 64 + b] = hn;
}

// ---------------------------------------------------------------------------
// Logits GEMM + fused argmax partial. 235 blocks x 512 threads (8 waves =
// 2 waves/SIMD at 1 block/CU). Tile M=64 x N=128, 4 K-teams of 192
// (6 chunks of BK=32), 8x8 register tiles split as {ty*4, 32+ty*4} x
// {tx*4, 64+tx*4} -> A reads broadcast (free), B reads 2-way (free).
// Epilogue: sequential 4-team sum + bias + argmax (deterministic).
// ---------------------------------------------------------------------------
__global__ __launch_bounds__(512) void klog(
    const float* __restrict__ hT, const float* __restrict__ outW,
    const float* __restrict__ outb, float* __restrict__ pval, int* __restrict__ pidx)
{
    // Per team: As[32][68] (2176 f) + Bs[32][132] (4224 f) = 6400 f.
    // 4 teams = 25600 f = 100 KiB. Epilogue overlays L[64*128] (8192 f).
    __shared__ float SMEM[25600];
    __shared__ float fvv[512];
    __shared__ int   fii[512];

    const int tid  = threadIdx.x;
    const int team = tid >> 7;          // 0..3 : K-range [team*192, +192)
    const int t128 = tid & 127;
    const int ty = t128 >> 4;           // 0..7
    const int tx = t128 & 15;           // 0..15
    const int cb = blockIdx.x;
    const int c0 = cb * 128;
    const int tk0 = team * 192;

    float* Ast = SMEM + team * 6400;        // [k][m] stride 68
    float* Bst = Ast + 2176;                // [k][n] stride 132

    const int gc = (c0 + t128 < VOCAB) ? (c0 + t128) : (VOCAB - 1);
    const float* wrow = outW + (size_t)gc * HID + tk0;
    const float* arow = hT + ((size_t)tk0 + ty) * 64 + tx * 4;

    float4 pa[4], pb[8];
    #pragma unroll
    for (int q = 0; q < 4; q++) pa[q] = *(const float4*)(arow + (size_t)(q * 8) * 64);
    #pragma unroll
    for (int kq = 0; kq < 8; kq++) pb[kq] = *(const float4*)(wrow + kq * 4);

    float acc[8][8];
    #pragma unroll
    for (int i = 0; i < 8; i++)
        #pragma unroll
        for (int j = 0; j < 8; j++) acc[i][j] = 0.f;

    for (int ch = 0; ch < 6; ch++) {
        __syncthreads();   // previous chunk's readers done
        #pragma unroll
        for (int q = 0; q < 4; q++)
            *(float4*)(Ast + (ty + 8 * q) * 68 + tx * 4) = pa[q];
        #pragma unroll
        for (int kq = 0; kq < 8; kq++) {
            Bst[(kq * 4 + 0) * 132 + t128] = pb[kq].x;
            Bst[(kq * 4 + 1) * 132 + t128] = pb[kq].y;
            Bst[(kq * 4 + 2) * 132 + t128] = pb[kq].z;
            Bst[(kq * 4 + 3) * 132 + t128] = pb[kq].w;
        }
        __syncthreads();   // LDS ready
        if (ch < 5) {
            const int off = (ch + 1) * 32;
            #pragma unroll
            for (int q = 0; q < 4; q++)
                pa[q] = *(const float4*)(arow + (size_t)(off + q * 8) * 64);
            #pragma unroll
            for (int kq = 0; kq < 8; kq++)
                pb[kq] = *(const float4*)(wrow + off + kq * 4);
        }
        #pragma unroll 4
        for (int kk = 0; kk < 32; kk++) {
            const float* Ar = Ast + kk * 68;
            const float* Br = Bst + kk * 132;
            float4 a0 = *(const float4*)(Ar + ty * 4);         // broadcast
            float4 a1 = *(const float4*)(Ar + 32 + ty * 4);    // broadcast
            float4 b0 = *(const float4*)(Br + tx * 4);         // 2-way (free)
            float4 b1 = *(const float4*)(Br + 64 + tx * 4);    // 2-way (free)
            float av[8] = {a0.x,a0.y,a0.z,a0.w,a1.x,a1.y,a1.z,a1.w};
            float bv[8] = {b0.x,b0.y,b0.z,b0.w,b1.x,b1.y,b1.z,b1.w};
            #pragma unroll
            for (int i = 0; i < 8; i++)
                #pragma unroll
                for (int j = 0; j < 8; j++)
                    acc[i][j] = fmaf(av[i], bv[j], acc[i][j]);
        }
    }

    // ---- epilogue: sequential team combine (deterministic) ----
    float* L = SMEM;   // 64 x 128
    __syncthreads();
    #pragma unroll
    for (int tm = 0; tm < 4; tm++) {
        if (team == tm) {
            #pragma unroll
            for (int i = 0; i < 8; i++) {
                const int m = (i < 4) ? (ty * 4 + i) : (32 + ty * 4 + i - 4);
                #pragma unroll
                for (int j = 0; j < 8; j++) {
                    const int n = (j < 4) ? (tx * 4 + j) : (64 + tx * 4 + j - 4);
                    if (tm == 0) L[m * 128 + n] = acc[i][j];
                    else         L[m * 128 + n] += acc[i][j];
                }
            }
        }
        __syncthreads();
    }

    {   // bias + argmax: thread: batch row b = tid>>3, segment seg = tid&7
        const int b = tid >> 3, seg = tid & 7;
        float bvv = -FLT_MAX; int bii = INT_MAX;
        #pragma unroll 4
        for (int cc = 0; cc < 16; cc++) {
            int col = seg * 16 + cc;
            int c = c0 + col;
            if (c < VOCAB) {
                float v = L[b * 128 + col] + outb[c];
                if (v > bvv) { bvv = v; bii = c; }   // ascending -> first occurrence
            }
        }
        fvv[tid] = bvv; fii[tid] = bii;
    }
    __syncthreads();
    if (tid < BB) {
        float bvv = -FLT_MAX; int bii = INT_MAX;
        #pragma unroll
        for (int s = 0; s < 8; s++) {
            float v = fvv[tid * 8 + s]; int ix = fii[tid * 8 + s];
            if (v > bvv || (v == bvv && ix < bii)) { bvv = v; bii = ix; }
        }
        pval[tid * NB_LOG + cb] = bvv;
        pidx[tid * NB_LOG + cb] = bii;
    }
}

// ---------------------------------------------------------------------------
// Finalize token for batch row b.
// ---------------------------------------------------------------------------
__global__ __launch_bounds__(256) void kfin(
    int step, const float* __restrict__ pval, const int* __restrict__ pidx,
    int* __restrict__ tok_ws, float* __restrict__ gen)
{
    const int b = blockIdx.x, tid = threadIdx.x;
    __shared__ float sv[256];
    __shared__ int   si[256];
    float bv = -FLT_MAX; int bi = INT_MAX;
    for (int p = tid; p < NB_LOG; p += 256) {
        float v = pval[b * NB_LOG + p]; int ix = pidx[b * NB_LOG + p];
        if (v > bv || (v == bv && ix < bi)) { bv = v; bi = ix; }
    }
    sv[tid] = bv; si[tid] = bi;
    __syncthreads();
    for (int st = 128; st; st >>= 1) {
        if (tid < st) {
            float v = sv[tid + st]; int ix = si[tid + st];
            if (v > sv[tid] || (v == sv[tid] && ix < si[tid])) { sv[tid] = v; si[tid] = ix; }
        }
        __syncthreads();
    }
    if (tid == 0) {
        tok_ws[b] = si[0];
        gen[b * TSTEPS + step] = (float)si[0];
    }
}

// ---------------------------------------------------------------------------
extern "C" void kernel_launch(void* const* d_in, const int* in_sizes, int n_in,
                              void* d_out, int out_size, void* d_ws, size_t ws_size,
                              hipStream_t stream)
{
    const float* feat = (const float*)d_in[0];
    const float* emb  = (const float*)d_in[1];
    const float* W_ih = (const float*)d_in[2];
    const float* W_hh = (const float*)d_in[3];
    const float* b_ih = (const float*)d_in[4];
    const float* b_hh = (const float*)d_in[5];
    const float* outW = (const float*)d_in[6];
    const float* outb = (const float*)d_in[7];
    const float* c1W  = (const float*)d_in[8];
    const float* c1b  = (const float*)d_in[9];
    const float* c2W  = (const float*)d_in[10];
    const float* c2b  = (const float*)d_in[11];
    (void)in_sizes; (void)n_in; (void)out_size; (void)ws_size;

    float* out = (float*)d_out;
    float* gen = out + BB * 2;                  // generated (64x32), as floats

    float* ws     = (float*)d_ws;
    float* hbuf   = ws;                               // 64*768  (b-major h)
    float* cbuf   = hbuf + BB * HID;                  // 64*768
    float* hT     = cbuf + BB * HID;                  // 768*64  (k-major h)
    float* gpart  = hT + HID * 64;                    // 8*64*3072
    float* pval   = gpart + (size_t)KSPLIT * BB * NG; // 64*235
    int*   pidx   = (int*)(pval + BB * NB_LOG);       // 64*235
    int*   tok    = pidx + BB * NB_LOG;               // 64
    float* hid_ws = (float*)(tok + BB);               // 64*512

    kc1<<<dim3(4, BB), 256, 0, stream>>>(feat, c1W, c1b, hid_ws);
    kc2<<<BB, 256, 0, stream>>>(hid_ws, c2W, c2b, out);
    kprep<<<dim3(HID * 64 / 256), 256, 0, stream>>>(feat, hT);

    for (int t = 0; t < TSTEPS; t++) {
        const float* h_in = (t == 0) ? feat : hbuf;
        kg1<<<dim3(48, KSPLIT), 256, 0, stream>>>(t, tok, emb, W_ih, W_hh, h_in, gpart);
        kc<<<dim3(192), 256, 0, stream>>>(t, gpart, b_ih, b_hh, cbuf, hbuf, hT);
        klog<<<dim3(NB_LOG), 512, 0, stream>>>(hT, outW, outb, pval, pidx);
        kfin<<<BB, 256, 0, stream>>>(t, pval, pidx, tok, gen);
    }
}